// Round 8
// baseline (259.588 us; speedup 1.0000x reference)
//
#include <hip/hip_runtime.h>
#include <math.h>

// nanoGPT Head: x[B,T,C] @ W{q,k,v}[C,H] -> causal softmax(QK^T/sqrt(H)) V
#define BB 8
#define TT 4096
#define CC 64
#define HH 128
#define NTH 256
#define XSTR 72        // proj x stride (bf16)
#define WSTR 72        // proj W stride (bf16)
// 128^-0.5 * log2(e): folded into Wq so S-scores are in log2 domain
#define QSCALE ((float)(0.08838834764831845 * 1.4426950408889634))

typedef __attribute__((ext_vector_type(8)))  short short8;    // 8 bf16 (MFMA A/B frag)
typedef __attribute__((ext_vector_type(4)))  float floatx4;   // 16x16 C/D frag
typedef __attribute__((ext_vector_type(16))) float floatx16;  // 32x32 C/D frag

__device__ __forceinline__ unsigned short f2bf(float f) {
    union { float f; unsigned int u; } un; un.f = f;
    unsigned int r = un.u + 0x7FFF + ((un.u >> 16) & 1);   // RNE
    return (unsigned short)(r >> 16);
}
// fast bf16 pair pack: round-half-up + v_perm (3 VALU ops vs ~9)
__device__ __forceinline__ unsigned int pack2bf_fast(float a, float b) {
    union { float f; unsigned int u; } ua, ub; ua.f = a; ub.f = b;
    return __builtin_amdgcn_perm(ub.u + 0x8000u, ua.u + 0x8000u, 0x07060302u);
}
__device__ __forceinline__ float bflo(unsigned int u) {
    union { unsigned int u; float f; } x; x.u = u << 16; return x.f;
}
__device__ __forceinline__ float bfhi(unsigned int u) {
    union { unsigned int u; float f; } x; x.u = u & 0xffff0000u; return x.f;
}

// async global->LDS, 16B per lane; lds dest = wave-uniform base + lane*16
__device__ __forceinline__ void gl_lds16(const void* g, void* l) {
    __builtin_amdgcn_global_load_lds(
        (const __attribute__((address_space(1))) unsigned int*)g,
        (__attribute__((address_space(3))) unsigned int*)l, 16, 0, 0);
}

// ---------------- Kernel 1: QKV projection via MFMA (unchanged from R7) ----------------
// Q -> [B,T,H] row-major bf16.
// K -> fragment-tiled: 64-key tile t = 16 KB @ (b*64+t)*16384 B; half kh at +kh*8192 B;
//      chunk: st*1024 + lane*16 B holds K[kh*32+(lane&31)][st*16+(lane>>5)*8 ..+8]
// V -> fragment-tiled: tile t = 16 KB @ (b*64+t)*16384 B; half kh at +kh*8192 B;
//      chunk: ht*2048 + ks*1024 + lane*16 B holds V^T[ht*32+(lane&31)][kh*32+ks*16+(lane>>5)*8 ..+8]
__global__ __launch_bounds__(NTH) void qkv_mfma(
    const float* __restrict__ x,
    const float* __restrict__ Wq, const float* __restrict__ Wk, const float* __restrict__ Wv,
    unsigned short* __restrict__ qb, unsigned short* __restrict__ Kf,
    unsigned short* __restrict__ Vf)
{
    __shared__ __align__(16) unsigned short xs[64 * XSTR];
    __shared__ __align__(16) unsigned short Wts[3 * HH * WSTR];

    const int tid  = threadIdx.x;
    const int w    = tid >> 6;
    const int lane = tid & 63;
    const int quad = lane >> 4;
    const int lr   = lane & 15;

    const int b    = blockIdx.x >> 6;
    const int kblk = blockIdx.x & 63;
    const int t0   = kblk * 64;
    const long long rbase = (long long)b * TT + t0;

#pragma unroll
    for (int i = 0; i < 4; ++i) {
        const int idx = tid + i * NTH;
        const int r = idx >> 4, c4 = idx & 15;
        const float4 v = *(const float4*)(x + (rbase + r) * CC + c4 * 4);
        unsigned short tmp[4] = { f2bf(v.x), f2bf(v.y), f2bf(v.z), f2bf(v.w) };
        *(unsigned long long*)&xs[r * XSTR + c4 * 4] = *(unsigned long long*)tmp;
    }
#pragma unroll
    for (int mat = 0; mat < 3; ++mat) {
        const float* W = mat == 0 ? Wq : (mat == 1 ? Wk : Wv);
        const float s = mat == 0 ? QSCALE : 1.0f;
#pragma unroll
        for (int i = 0; i < 32; ++i) {
            const int idx = tid + i * NTH;
            const int c = idx >> 7, h = idx & 127;
            Wts[(mat * HH + h) * WSTR + c] = f2bf(W[idx] * s);
        }
    }
    __syncthreads();

    const short8 bx0 = *(const short8*)&xs[(w * 16 + lr) * XSTR + quad * 8];
    const short8 bx1 = *(const short8*)&xs[(w * 16 + lr) * XSTR + 32 + quad * 8];

    // Q
    {
        const unsigned short* Wrow = Wts;
#pragma unroll
        for (int ht = 0; ht < 8; ++ht) {
            const short8 aw0 = *(const short8*)(Wrow + (ht * 16 + lr) * WSTR + quad * 8);
            const short8 aw1 = *(const short8*)(Wrow + (ht * 16 + lr) * WSTR + 32 + quad * 8);
            floatx4 acc = (floatx4)0.f;
            acc = __builtin_amdgcn_mfma_f32_16x16x32_bf16(aw0, bx0, acc, 0, 0, 0);
            acc = __builtin_amdgcn_mfma_f32_16x16x32_bf16(aw1, bx1, acc, 0, 0, 0);
            ushort4 st = { f2bf(acc[0]), f2bf(acc[1]), f2bf(acc[2]), f2bf(acc[3]) };
            *(ushort4*)(qb + (rbase + w * 16 + lr) * HH + ht * 16 + quad * 4) = st;
        }
    }
    // K fragment-tiled
    {
        const unsigned short* Wrow = Wts + 1 * HH * WSTR;
        const int khp = w >> 1;
        const int lqp = (w & 1) * 16 + lr;
        unsigned short* kdst = Kf + ((long long)((b * 64 + kblk) * 2 + khp)) * 4096
                             + ((quad >> 1) & 1) * 256 + lqp * 8 + (quad & 1) * 4;
#pragma unroll
        for (int ht = 0; ht < 8; ++ht) {
            const short8 aw0 = *(const short8*)(Wrow + (ht * 16 + lr) * WSTR + quad * 8);
            const short8 aw1 = *(const short8*)(Wrow + (ht * 16 + lr) * WSTR + 32 + quad * 8);
            floatx4 acc = (floatx4)0.f;
            acc = __builtin_amdgcn_mfma_f32_16x16x32_bf16(aw0, bx0, acc, 0, 0, 0);
            acc = __builtin_amdgcn_mfma_f32_16x16x32_bf16(aw1, bx1, acc, 0, 0, 0);
            ushort4 st = { f2bf(acc[0]), f2bf(acc[1]), f2bf(acc[2]), f2bf(acc[3]) };
            *(ushort4*)(kdst + ht * 512) = st;
        }
    }
    // V fragment-tiled
    {
        const unsigned short* Wrow = Wts + 2 * HH * WSTR;
        const int khv = w >> 1, ksv = w & 1, lsv = (quad >> 1) & 1;
        unsigned short* vdst = Vf + (long long)(b * 64 + kblk) * 8192 + khv * 4096
                             + ksv * 512 + lsv * 256 + (quad & 1) * 4;
#pragma unroll
        for (int htp = 0; htp < 8; ++htp) {
            const short8 bw0 = *(const short8*)(Wrow + (htp * 16 + lr) * WSTR + quad * 8);
            const short8 bw1 = *(const short8*)(Wrow + (htp * 16 + lr) * WSTR + 32 + quad * 8);
            floatx4 acc = (floatx4)0.f;
            acc = __builtin_amdgcn_mfma_f32_16x16x32_bf16(bx0, bw0, acc, 0, 0, 0);
            acc = __builtin_amdgcn_mfma_f32_16x16x32_bf16(bx1, bw1, acc, 0, 0, 0);
            ushort4 st = { f2bf(acc[0]), f2bf(acc[1]), f2bf(acc[2]), f2bf(acc[3]) };
            *(ushort4*)(vdst + (htp >> 1) * 1024 + ((htp & 1) * 16 + lr) * 8) = st;
        }
    }
}

// wave-assigned DMA of one 32 KB K+V tile into an LDS buffer (w<4: K, w>=4: V)
__device__ __forceinline__ void dma_tile(
    const unsigned char* __restrict__ Ksrc, const unsigned char* __restrict__ Vsrc,
    long long kt, unsigned char* buf, int w, int lane)
{
    const unsigned char* src;
    unsigned char* dst;
    if (w < 4) {
        src = Ksrc + kt * 16384 + w * 4096 + lane * 16;
        dst = buf + w * 4096;
    } else {
        src = Vsrc + kt * 16384 + (w - 4) * 4096 + lane * 16;
        dst = buf + 16384 + (w - 4) * 4096;
    }
#pragma unroll
    for (int i = 0; i < 4; ++i)
        gl_lds16(src + i * 1024, dst + i * 1024);
}

// ---------------- Kernel 2: split-K flash, LDS-staged K/V (DMA dbuf), 8 waves ----------------
// Block = (b, qtile of 128 q, chunk c of 4). Wave w: qh = w>>1 (q quarter), kh = w&1 (key half).
// 32x32x16: A[m=lane&31][k=(lane>>5)*8+j]; B[k][n=lane&31]; C/D: col=lane&31,
// row=(reg&3)+8*(reg>>2)+4*(lane>>5). No-max softmax; partials linear; combine kernel finishes.
__global__ __launch_bounds__(512, 4) void flash_splitk(
    const unsigned short* __restrict__ qb,
    const unsigned short* __restrict__ Kf,
    const unsigned short* __restrict__ Vf,
    unsigned short* __restrict__ Ob, float* __restrict__ Lb)
{
    __shared__ __align__(16) unsigned char KV[2][32768];   // [buf][K 16KB | V 16KB]
    __shared__ float Lx[8][32];

    const int tid  = threadIdx.x;
    const int w    = tid >> 6;        // 0..7
    const int lane = tid & 63;
    const int lq   = lane & 31;
    const int ls   = lane >> 5;
    const int kh   = w & 1;
    const int qh   = w >> 1;          // 0..3

    const int id     = blockIdx.x;
    const int qtile  = 31 - (id >> 5);            // heavy first
    const int rem    = id & 31;
    const int b      = rem >> 2;
    const int c      = rem & 3;
    const int ntiles = 2 * qtile + 2;             // 64-key tiles in causal range
    const int len    = (ntiles + 3) >> 2;
    const int lo     = c * len;
    if (lo >= ntiles) return;                     // empty chunk (block-uniform)
    const int hi0 = lo + len - 1;
    const int hi  = hi0 < ntiles - 1 ? hi0 : ntiles - 1;

    const int q0 = qtile * 128;
    const long long baset = (long long)b * TT;
    const unsigned char* Ksrc = (const unsigned char*)Kf + (long long)(b * 64) * 16384;
    const unsigned char* Vsrc = (const unsigned char*)Vf + (long long)(b * 64) * 16384;

    dma_tile(Ksrc, Vsrc, lo, KV[0], w, lane);     // tile lo -> buf 0 (drained by first barrier)

    // Q fragments: row q0+qh*32+lq, d = st*16 + ls*8 + j
    short8 aq[8];
    {
        const unsigned short* qrp = qb + (baset + q0 + qh * 32 + lq) * HH + ls * 8;
#pragma unroll
        for (int st = 0; st < 8; ++st)
            aq[st] = *(const short8*)(qrp + st * 16);
    }

    floatx16 o_acc[4];   // O^T partial: h = ht*32 + row(reg,ls), q = qh*32+lq (kh's keys only)
#pragma unroll
    for (int ht = 0; ht < 4; ++ht) o_acc[ht] = (floatx16)0.f;
    float l_lane = 0.f;

    for (int kt = lo; kt <= hi; ++kt) {
        const int cb = (kt - lo) & 1;
        __syncthreads();   // compiler-inserted vmcnt(0) drains buf[cb] DMA; prior readers of buf[cb^1] done
        if (kt < hi)       // prefetch next tile: in flight across this whole iteration
            dma_tile(Ksrc, Vsrc, kt + 1, KV[cb ^ 1], w, lane);

        const int D = q0 + qh * 32 - kt * 64 - kh * 32;   // q_start - k_start (wave-uniform)
        if (D > -32) {
            const unsigned short* Kt = (const unsigned short*)&KV[cb][0]     + kh * 4096;
            const unsigned short* Vt = (const unsigned short*)&KV[cb][16384] + kh * 4096;

            short8 kfr[8], vfr[8];
#pragma unroll
            for (int st = 0; st < 8; ++st)
                kfr[st] = *(const short8*)(Kt + st * 512 + lane * 8);
#pragma unroll
            for (int i = 0; i < 8; ++i)
                vfr[i] = *(const short8*)(Vt + (i >> 1) * 1024 + (i & 1) * 512 + lane * 8);

            // S^T = K Q^T
            floatx16 s_acc = (floatx16)0.f;
#pragma unroll
            for (int st = 0; st < 8; ++st)
                s_acc = __builtin_amdgcn_mfma_f32_32x32x16_bf16(kfr[st], aq[st], s_acc, 0, 0, 0);

            // p = exp2(s), causal mask (kk <= lq + D), l accumulation
            float p[16];
            if (D < 31) {
#pragma unroll
                for (int reg = 0; reg < 16; ++reg) {
                    const int kk = (reg & 3) + 8 * (reg >> 2) + 4 * ls;
                    p[reg] = (kk <= lq + D) ? exp2f(s_acc[reg]) : 0.f;
                }
            } else {
#pragma unroll
                for (int reg = 0; reg < 16; ++reg)
                    p[reg] = exp2f(s_acc[reg]);
            }
#pragma unroll
            for (int reg = 0; reg < 16; ++reg) l_lane += p[reg];

            // P C-layout -> B-layout in-register
            unsigned int g[8], pg[8];
#pragma unroll
            for (int i = 0; i < 8; ++i) g[i] = pack2bf_fast(p[2 * i], p[2 * i + 1]);
#pragma unroll
            for (int i = 0; i < 8; ++i) pg[i] = __shfl_xor((int)g[i], 32);
            short8 bp[2];
#pragma unroll
            for (int ks = 0; ks < 2; ++ks) {
                union { short8 s; unsigned int u[4]; } fr;
                const int bs = ks * 4;
                if (ls == 0) {
                    fr.u[0] = g[bs];      fr.u[1] = g[bs + 1];
                    fr.u[2] = pg[bs];     fr.u[3] = pg[bs + 1];
                } else {
                    fr.u[0] = pg[bs + 2]; fr.u[1] = pg[bs + 3];
                    fr.u[2] = g[bs + 2];  fr.u[3] = g[bs + 3];
                }
                bp[ks] = fr.s;
            }

            // O^T += V^T P^T
#pragma unroll
            for (int ht = 0; ht < 4; ++ht) {
                o_acc[ht] = __builtin_amdgcn_mfma_f32_32x32x16_bf16(vfr[ht * 2 + 0], bp[0], o_acc[ht], 0, 0, 0);
                o_acc[ht] = __builtin_amdgcn_mfma_f32_32x32x16_bf16(vfr[ht * 2 + 1], bp[1], o_acc[ht], 0, 0, 0);
            }
        }
    }

    // ---- epilogue: fold ls, exchange kh halves via LDS (KV dead), write partial Ob + Lb ----
    const float l2 = l_lane + __shfl_xor(l_lane, 32);
    if (lane < 32) Lx[w][lq] = l2;
    __syncthreads();                               // all KV readers done; Lx visible
    float* ex = (float*)&KV[0][0] + qh * 4096;     // 16 KB fp32 region per qh
    if (kh == 1) {
        float* e = ex + lane * 64;
#pragma unroll
        for (int ht = 0; ht < 4; ++ht)
#pragma unroll
            for (int rg = 0; rg < 4; ++rg) {
                float4 v = make_float4(o_acc[ht][rg * 4 + 0], o_acc[ht][rg * 4 + 1],
                                       o_acc[ht][rg * 4 + 2], o_acc[ht][rg * 4 + 3]);
                *(float4*)&e[ht * 16 + rg * 4] = v;
            }
    }
    __syncthreads();
    if (kh == 0) {
        const int pid = ((b * 32 + qtile) << 2) + c;
        Lb[pid * 128 + qh * 32 + lq] = Lx[2 * qh][lq] + Lx[2 * qh + 1][lq];
        const float* e = ex + lane * 64;
        unsigned short* od = Ob + (long long)pid * 16384 + (qh * 32 + lq) * HH;
#pragma unroll
        for (int ht = 0; ht < 4; ++ht)
#pragma unroll
            for (int rg = 0; rg < 4; ++rg) {
                const float4 pv = *(const float4*)&e[ht * 16 + rg * 4];
                uint2 st;
                st.x = pack2bf_fast(o_acc[ht][rg * 4 + 0] + pv.x, o_acc[ht][rg * 4 + 1] + pv.y);
                st.y = pack2bf_fast(o_acc[ht][rg * 4 + 2] + pv.z, o_acc[ht][rg * 4 + 3] + pv.w);
                *(uint2*)(od + ht * 32 + rg * 8 + 4 * ls) = st;
            }
    }
}

// ---------------- Kernel 3: combine partials, divide by l ----------------
// Block = (b, 64-q subtile). Sums <=4 chunk partials, writes out fp32.
__global__ __launch_bounds__(NTH) void combine(
    const unsigned short* __restrict__ Ob, const float* __restrict__ Lb,
    float* __restrict__ out)
{
    const int id = blockIdx.x;
    const int b = id & 7, qt64 = id >> 3;
    const int qtile = qt64 >> 1, sub = qt64 & 1;
    const int ntiles = 2 * qtile + 2;
    const int len = (ntiles + 3) >> 2;
    const int tid = threadIdx.x;
    const int q = tid >> 2;            // 0..63
    const int hg = tid & 3;
    const int pid0 = (b * 32 + qtile) << 2;

    float acc[32];
#pragma unroll
    for (int i = 0; i < 32; ++i) acc[i] = 0.f;
    float ltot = 0.f;

#pragma unroll
    for (int c = 0; c < 4; ++c) {
        if (c * len >= ntiles) break;
        ltot += Lb[(pid0 + c) * 128 + sub * 64 + q];
        const uint4* src = (const uint4*)(Ob + (long long)(pid0 + c) * 16384
                                          + (sub * 64 + q) * HH + hg * 32);
#pragma unroll
        for (int g = 0; g < 4; ++g) {
            const uint4 d = src[g];
            acc[g * 8 + 0] += bflo(d.x); acc[g * 8 + 1] += bfhi(d.x);
            acc[g * 8 + 2] += bflo(d.y); acc[g * 8 + 3] += bfhi(d.y);
            acc[g * 8 + 4] += bflo(d.z); acc[g * 8 + 5] += bfhi(d.z);
            acc[g * 8 + 6] += bflo(d.w); acc[g * 8 + 7] += bfhi(d.w);
        }
    }
    const float inv = 1.f / ltot;
    float* op = out + ((long long)b * TT + qtile * 128 + sub * 64 + q) * HH + hg * 32;
#pragma unroll
    for (int g = 0; g < 8; ++g) {
        float4 st = make_float4(acc[g * 4 + 0] * inv, acc[g * 4 + 1] * inv,
                                acc[g * 4 + 2] * inv, acc[g * 4 + 3] * inv);
        *(float4*)(op + g * 4) = st;
    }
}

extern "C" void kernel_launch(void* const* d_in, const int* in_sizes, int n_in,
                              void* d_out, int out_size, void* d_ws, size_t ws_size,
                              hipStream_t stream)
{
    const float* x  = (const float*)d_in[0];
    const float* Wq = (const float*)d_in[1];
    const float* Wk = (const float*)d_in[2];
    const float* Wv = (const float*)d_in[3];
    float* out = (float*)d_out;

    const long long n = (long long)BB * TT * HH;   // 4,194,304
    unsigned short* qb = (unsigned short*)d_ws;
    unsigned short* Kf = qb + n;
    unsigned short* Vf = Kf + n;
    unsigned short* Ob = Vf + n;                   // 1024 * 16384 bf16 = 33.5 MB
    float*          Lb = (float*)(Ob + (long long)1024 * 16384);  // 1024*128 fp32

    qkv_mfma<<<BB * (TT / 64), NTH, 0, stream>>>(x, Wq, Wk, Wv, qb, Kf, Vf);
    flash_splitk<<<1024, 512, 0, stream>>>(qb, Kf, Vf, Ob, Lb);
    combine<<<BB * 64, NTH, 0, stream>>>(Ob, Lb, out);
}

// Round 9
// 171.924 us; speedup vs baseline: 1.5099x; 1.5099x over previous
//
#include <hip/hip_runtime.h>
#include <math.h>

// nanoGPT Head: x[B,T,C] @ W{q,k,v}[C,H] -> causal softmax(QK^T/sqrt(H)) V
#define BB 8
#define TT 4096
#define CC 64
#define HH 128
#define NTH 256
#define XSTR 72        // proj x stride (bf16)
#define WSTR 72        // proj W stride (bf16)
// 128^-0.5 * log2(e): folded into Wq so S-scores are in log2 domain
#define QSCALE ((float)(0.08838834764831845 * 1.4426950408889634))

typedef __attribute__((ext_vector_type(8)))  short short8;    // 8 bf16 (MFMA A/B frag)
typedef __attribute__((ext_vector_type(4)))  float floatx4;   // 16x16 C/D frag
typedef __attribute__((ext_vector_type(16))) float floatx16;  // 32x32 C/D frag

__device__ __forceinline__ unsigned short f2bf(float f) {
    union { float f; unsigned int u; } un; un.f = f;
    unsigned int r = un.u + 0x7FFF + ((un.u >> 16) & 1);   // RNE
    return (unsigned short)(r >> 16);
}
// fast bf16 pair pack: round-half-up + v_perm (3 VALU ops vs ~9)
__device__ __forceinline__ unsigned int pack2bf_fast(float a, float b) {
    union { float f; unsigned int u; } ua, ub; ua.f = a; ub.f = b;
    return __builtin_amdgcn_perm(ub.u + 0x8000u, ua.u + 0x8000u, 0x07060302u);
}
__device__ __forceinline__ float bflo(unsigned int u) {
    union { unsigned int u; float f; } x; x.u = u << 16; return x.f;
}
__device__ __forceinline__ float bfhi(unsigned int u) {
    union { unsigned int u; float f; } x; x.u = u & 0xffff0000u; return x.f;
}

// async global->LDS, 16B per lane; lds dest = wave-uniform base + lane*16
__device__ __forceinline__ void gl_lds16(const void* g, void* l) {
    __builtin_amdgcn_global_load_lds(
        (const __attribute__((address_space(1))) unsigned int*)g,
        (__attribute__((address_space(3))) unsigned int*)l, 16, 0, 0);
}

// ---------------- Kernel 1: QKV projection via MFMA (unchanged) ----------------
// Q -> [B,T,H] row-major bf16.
// K -> fragment-tiled: 64-key tile t = 16 KB @ (b*64+t)*16384 B; half kh at +kh*8192 B;
//      chunk: st*1024 + lane*16 B holds K[kh*32+(lane&31)][st*16+(lane>>5)*8 ..+8]
// V -> fragment-tiled: tile t = 16 KB @ (b*64+t)*16384 B; half kh at +kh*8192 B;
//      chunk: ht*2048 + ks*1024 + lane*16 B holds V^T[ht*32+(lane&31)][kh*32+ks*16+(lane>>5)*8 ..+8]
__global__ __launch_bounds__(NTH) void qkv_mfma(
    const float* __restrict__ x,
    const float* __restrict__ Wq, const float* __restrict__ Wk, const float* __restrict__ Wv,
    unsigned short* __restrict__ qb, unsigned short* __restrict__ Kf,
    unsigned short* __restrict__ Vf)
{
    __shared__ __align__(16) unsigned short xs[64 * XSTR];
    __shared__ __align__(16) unsigned short Wts[3 * HH * WSTR];

    const int tid  = threadIdx.x;
    const int w    = tid >> 6;
    const int lane = tid & 63;
    const int quad = lane >> 4;
    const int lr   = lane & 15;

    const int b    = blockIdx.x >> 6;
    const int kblk = blockIdx.x & 63;
    const int t0   = kblk * 64;
    const long long rbase = (long long)b * TT + t0;

#pragma unroll
    for (int i = 0; i < 4; ++i) {
        const int idx = tid + i * NTH;
        const int r = idx >> 4, c4 = idx & 15;
        const float4 v = *(const float4*)(x + (rbase + r) * CC + c4 * 4);
        unsigned short tmp[4] = { f2bf(v.x), f2bf(v.y), f2bf(v.z), f2bf(v.w) };
        *(unsigned long long*)&xs[r * XSTR + c4 * 4] = *(unsigned long long*)tmp;
    }
#pragma unroll
    for (int mat = 0; mat < 3; ++mat) {
        const float* W = mat == 0 ? Wq : (mat == 1 ? Wk : Wv);
        const float s = mat == 0 ? QSCALE : 1.0f;
#pragma unroll
        for (int i = 0; i < 32; ++i) {
            const int idx = tid + i * NTH;
            const int c = idx >> 7, h = idx & 127;
            Wts[(mat * HH + h) * WSTR + c] = f2bf(W[idx] * s);
        }
    }
    __syncthreads();

    const short8 bx0 = *(const short8*)&xs[(w * 16 + lr) * XSTR + quad * 8];
    const short8 bx1 = *(const short8*)&xs[(w * 16 + lr) * XSTR + 32 + quad * 8];

    // Q
    {
        const unsigned short* Wrow = Wts;
#pragma unroll
        for (int ht = 0; ht < 8; ++ht) {
            const short8 aw0 = *(const short8*)(Wrow + (ht * 16 + lr) * WSTR + quad * 8);
            const short8 aw1 = *(const short8*)(Wrow + (ht * 16 + lr) * WSTR + 32 + quad * 8);
            floatx4 acc = (floatx4)0.f;
            acc = __builtin_amdgcn_mfma_f32_16x16x32_bf16(aw0, bx0, acc, 0, 0, 0);
            acc = __builtin_amdgcn_mfma_f32_16x16x32_bf16(aw1, bx1, acc, 0, 0, 0);
            ushort4 st = { f2bf(acc[0]), f2bf(acc[1]), f2bf(acc[2]), f2bf(acc[3]) };
            *(ushort4*)(qb + (rbase + w * 16 + lr) * HH + ht * 16 + quad * 4) = st;
        }
    }
    // K fragment-tiled
    {
        const unsigned short* Wrow = Wts + 1 * HH * WSTR;
        const int khp = w >> 1;
        const int lqp = (w & 1) * 16 + lr;
        unsigned short* kdst = Kf + ((long long)((b * 64 + kblk) * 2 + khp)) * 4096
                             + ((quad >> 1) & 1) * 256 + lqp * 8 + (quad & 1) * 4;
#pragma unroll
        for (int ht = 0; ht < 8; ++ht) {
            const short8 aw0 = *(const short8*)(Wrow + (ht * 16 + lr) * WSTR + quad * 8);
            const short8 aw1 = *(const short8*)(Wrow + (ht * 16 + lr) * WSTR + 32 + quad * 8);
            floatx4 acc = (floatx4)0.f;
            acc = __builtin_amdgcn_mfma_f32_16x16x32_bf16(aw0, bx0, acc, 0, 0, 0);
            acc = __builtin_amdgcn_mfma_f32_16x16x32_bf16(aw1, bx1, acc, 0, 0, 0);
            ushort4 st = { f2bf(acc[0]), f2bf(acc[1]), f2bf(acc[2]), f2bf(acc[3]) };
            *(ushort4*)(kdst + ht * 512) = st;
        }
    }
    // V fragment-tiled
    {
        const unsigned short* Wrow = Wts + 2 * HH * WSTR;
        const int khv = w >> 1, ksv = w & 1, lsv = (quad >> 1) & 1;
        unsigned short* vdst = Vf + (long long)(b * 64 + kblk) * 8192 + khv * 4096
                             + ksv * 512 + lsv * 256 + (quad & 1) * 4;
#pragma unroll
        for (int htp = 0; htp < 8; ++htp) {
            const short8 bw0 = *(const short8*)(Wrow + (htp * 16 + lr) * WSTR + quad * 8);
            const short8 bw1 = *(const short8*)(Wrow + (htp * 16 + lr) * WSTR + 32 + quad * 8);
            floatx4 acc = (floatx4)0.f;
            acc = __builtin_amdgcn_mfma_f32_16x16x32_bf16(bx0, bw0, acc, 0, 0, 0);
            acc = __builtin_amdgcn_mfma_f32_16x16x32_bf16(bx1, bw1, acc, 0, 0, 0);
            ushort4 st = { f2bf(acc[0]), f2bf(acc[1]), f2bf(acc[2]), f2bf(acc[3]) };
            *(ushort4*)(vdst + (htp >> 1) * 1024 + ((htp & 1) * 16 + lr) * 8) = st;
        }
    }
}

// wave-assigned DMA of one 32 KB K+V tile into an LDS buffer (w<4: K, w>=4: V)
__device__ __forceinline__ void dma_tile(
    const unsigned char* __restrict__ Ksrc, const unsigned char* __restrict__ Vsrc,
    long long kt, unsigned char* buf, int w, int lane)
{
    const unsigned char* src;
    unsigned char* dst;
    if (w < 4) {
        src = Ksrc + kt * 16384 + w * 4096 + lane * 16;
        dst = buf + w * 4096;
    } else {
        src = Vsrc + kt * 16384 + (w - 4) * 4096 + lane * 16;
        dst = buf + 16384 + (w - 4) * 4096;
    }
#pragma unroll
    for (int i = 0; i < 4; ++i)
        gl_lds16(src + i * 1024, dst + i * 1024);
}

// ---------------- Kernel 2: split-K flash, LDS-staged K/V (DMA dbuf), 8 waves ----------------
// Block = (b, qtile of 128 q, chunk c of 4). Wave w: qh = w>>1 (q quarter), kh = w&1 (key half).
// __launch_bounds__(512, 2): 2 waves/EU -> 256-reg unified budget; body needs ~176
// (96 VGPR + 80 AGPR) -> NO spill. (512,4) in R8 forced 128 regs -> 247 MB scratch traffic.
__global__ __launch_bounds__(512, 2) void flash_splitk(
    const unsigned short* __restrict__ qb,
    const unsigned short* __restrict__ Kf,
    const unsigned short* __restrict__ Vf,
    unsigned short* __restrict__ Ob, float* __restrict__ Lb)
{
    __shared__ __align__(16) unsigned char KV[2][32768];   // [buf][K 16KB | V 16KB]
    __shared__ float Lx[8][32];

    const int tid  = threadIdx.x;
    const int w    = tid >> 6;        // 0..7
    const int lane = tid & 63;
    const int lq   = lane & 31;
    const int ls   = lane >> 5;
    const int kh   = w & 1;
    const int qh   = w >> 1;          // 0..3

    const int id     = blockIdx.x;
    const int qtile  = 31 - (id >> 5);            // heavy first
    const int rem    = id & 31;
    const int b      = rem >> 2;
    const int c      = rem & 3;
    const int ntiles = 2 * qtile + 2;             // 64-key tiles in causal range
    const int len    = (ntiles + 3) >> 2;
    const int lo     = c * len;
    if (lo >= ntiles) return;                     // empty chunk (block-uniform)
    const int hi0 = lo + len - 1;
    const int hi  = hi0 < ntiles - 1 ? hi0 : ntiles - 1;

    const int q0 = qtile * 128;
    const long long baset = (long long)b * TT;
    const unsigned char* Ksrc = (const unsigned char*)Kf + (long long)(b * 64) * 16384;
    const unsigned char* Vsrc = (const unsigned char*)Vf + (long long)(b * 64) * 16384;

    dma_tile(Ksrc, Vsrc, lo, KV[0], w, lane);     // tile lo -> buf 0 (drained by first barrier)

    // Q fragments: row q0+qh*32+lq, d = st*16 + ls*8 + j
    short8 aq[8];
    {
        const unsigned short* qrp = qb + (baset + q0 + qh * 32 + lq) * HH + ls * 8;
#pragma unroll
        for (int st = 0; st < 8; ++st)
            aq[st] = *(const short8*)(qrp + st * 16);
    }

    floatx16 o_acc[4];   // O^T partial: h = ht*32 + row(reg,ls), q = qh*32+lq (kh's keys only)
#pragma unroll
    for (int ht = 0; ht < 4; ++ht) o_acc[ht] = (floatx16)0.f;
    float l_lane = 0.f;

    for (int kt = lo; kt <= hi; ++kt) {
        const int cb = (kt - lo) & 1;
        __syncthreads();   // compiler-inserted vmcnt(0) drains buf[cb] DMA; prior readers of buf[cb^1] done
        if (kt < hi)       // prefetch next tile: in flight across this whole iteration
            dma_tile(Ksrc, Vsrc, kt + 1, KV[cb ^ 1], w, lane);

        const int D = q0 + qh * 32 - kt * 64 - kh * 32;   // q_start - k_start (wave-uniform)
        if (D > -32) {
            const unsigned short* Kt = (const unsigned short*)&KV[cb][0]     + kh * 4096;
            const unsigned short* Vt = (const unsigned short*)&KV[cb][16384] + kh * 4096;

            short8 kfr[8], vfr[8];
#pragma unroll
            for (int st = 0; st < 8; ++st)
                kfr[st] = *(const short8*)(Kt + st * 512 + lane * 8);
#pragma unroll
            for (int i = 0; i < 8; ++i)
                vfr[i] = *(const short8*)(Vt + (i >> 1) * 1024 + (i & 1) * 512 + lane * 8);

            // S^T = K Q^T
            floatx16 s_acc = (floatx16)0.f;
#pragma unroll
            for (int st = 0; st < 8; ++st)
                s_acc = __builtin_amdgcn_mfma_f32_32x32x16_bf16(kfr[st], aq[st], s_acc, 0, 0, 0);

            // p = exp2(s), causal mask (kk <= lq + D), l accumulation
            float p[16];
            if (D < 31) {
#pragma unroll
                for (int reg = 0; reg < 16; ++reg) {
                    const int kk = (reg & 3) + 8 * (reg >> 2) + 4 * ls;
                    p[reg] = (kk <= lq + D) ? exp2f(s_acc[reg]) : 0.f;
                }
            } else {
#pragma unroll
                for (int reg = 0; reg < 16; ++reg)
                    p[reg] = exp2f(s_acc[reg]);
            }
#pragma unroll
            for (int reg = 0; reg < 16; ++reg) l_lane += p[reg];

            // P C-layout -> B-layout in-register
            unsigned int g[8], pg[8];
#pragma unroll
            for (int i = 0; i < 8; ++i) g[i] = pack2bf_fast(p[2 * i], p[2 * i + 1]);
#pragma unroll
            for (int i = 0; i < 8; ++i) pg[i] = __shfl_xor((int)g[i], 32);
            short8 bp[2];
#pragma unroll
            for (int ks = 0; ks < 2; ++ks) {
                union { short8 s; unsigned int u[4]; } fr;
                const int bs = ks * 4;
                if (ls == 0) {
                    fr.u[0] = g[bs];      fr.u[1] = g[bs + 1];
                    fr.u[2] = pg[bs];     fr.u[3] = pg[bs + 1];
                } else {
                    fr.u[0] = pg[bs + 2]; fr.u[1] = pg[bs + 3];
                    fr.u[2] = g[bs + 2];  fr.u[3] = g[bs + 3];
                }
                bp[ks] = fr.s;
            }

            // O^T += V^T P^T
#pragma unroll
            for (int ht = 0; ht < 4; ++ht) {
                o_acc[ht] = __builtin_amdgcn_mfma_f32_32x32x16_bf16(vfr[ht * 2 + 0], bp[0], o_acc[ht], 0, 0, 0);
                o_acc[ht] = __builtin_amdgcn_mfma_f32_32x32x16_bf16(vfr[ht * 2 + 1], bp[1], o_acc[ht], 0, 0, 0);
            }
        }
    }

    // ---- epilogue: fold ls, exchange kh halves via LDS (KV dead), write partial Ob + Lb ----
    const float l2 = l_lane + __shfl_xor(l_lane, 32);
    if (lane < 32) Lx[w][lq] = l2;
    __syncthreads();                               // all KV readers done; Lx visible
    float* ex = (float*)&KV[0][0] + qh * 4096;     // 16 KB fp32 region per qh
    if (kh == 1) {
        float* e = ex + lane * 64;
#pragma unroll
        for (int ht = 0; ht < 4; ++ht)
#pragma unroll
            for (int rg = 0; rg < 4; ++rg) {
                float4 v = make_float4(o_acc[ht][rg * 4 + 0], o_acc[ht][rg * 4 + 1],
                                       o_acc[ht][rg * 4 + 2], o_acc[ht][rg * 4 + 3]);
                *(float4*)&e[ht * 16 + rg * 4] = v;
            }
    }
    __syncthreads();
    if (kh == 0) {
        const int pid = ((b * 32 + qtile) << 2) + c;
        Lb[pid * 128 + qh * 32 + lq] = Lx[2 * qh][lq] + Lx[2 * qh + 1][lq];
        const float* e = ex + lane * 64;
        unsigned short* od = Ob + (long long)pid * 16384 + (qh * 32 + lq) * HH;
#pragma unroll
        for (int ht = 0; ht < 4; ++ht)
#pragma unroll
            for (int rg = 0; rg < 4; ++rg) {
                const float4 pv = *(const float4*)&e[ht * 16 + rg * 4];
                uint2 st;
                st.x = pack2bf_fast(o_acc[ht][rg * 4 + 0] + pv.x, o_acc[ht][rg * 4 + 1] + pv.y);
                st.y = pack2bf_fast(o_acc[ht][rg * 4 + 2] + pv.z, o_acc[ht][rg * 4 + 3] + pv.w);
                *(uint2*)(od + ht * 32 + rg * 8 + 4 * ls) = st;
            }
    }
}

// ---------------- Kernel 3: combine partials, divide by l ----------------
// Block = (b, 64-q subtile). Sums <=4 chunk partials, writes out fp32.
__global__ __launch_bounds__(NTH) void combine(
    const unsigned short* __restrict__ Ob, const float* __restrict__ Lb,
    float* __restrict__ out)
{
    const int id = blockIdx.x;
    const int b = id & 7, qt64 = id >> 3;
    const int qtile = qt64 >> 1, sub = qt64 & 1;
    const int ntiles = 2 * qtile + 2;
    const int len = (ntiles + 3) >> 2;
    const int tid = threadIdx.x;
    const int q = tid >> 2;            // 0..63
    const int hg = tid & 3;
    const int pid0 = (b * 32 + qtile) << 2;

    float acc[32];
#pragma unroll
    for (int i = 0; i < 32; ++i) acc[i] = 0.f;
    float ltot = 0.f;

#pragma unroll
    for (int c = 0; c < 4; ++c) {
        if (c * len >= ntiles) break;
        ltot += Lb[(pid0 + c) * 128 + sub * 64 + q];
        const uint4* src = (const uint4*)(Ob + (long long)(pid0 + c) * 16384
                                          + (sub * 64 + q) * HH + hg * 32);
#pragma unroll
        for (int g = 0; g < 4; ++g) {
            const uint4 d = src[g];
            acc[g * 8 + 0] += bflo(d.x); acc[g * 8 + 1] += bfhi(d.x);
            acc[g * 8 + 2] += bflo(d.y); acc[g * 8 + 3] += bfhi(d.y);
            acc[g * 8 + 4] += bflo(d.z); acc[g * 8 + 5] += bfhi(d.z);
            acc[g * 8 + 6] += bflo(d.w); acc[g * 8 + 7] += bfhi(d.w);
        }
    }
    const float inv = 1.f / ltot;
    float* op = out + ((long long)b * TT + qtile * 128 + sub * 64 + q) * HH + hg * 32;
#pragma unroll
    for (int g = 0; g < 8; ++g) {
        float4 st = make_float4(acc[g * 4 + 0] * inv, acc[g * 4 + 1] * inv,
                                acc[g * 4 + 2] * inv, acc[g * 4 + 3] * inv);
        *(float4*)(op + g * 4) = st;
    }
}

extern "C" void kernel_launch(void* const* d_in, const int* in_sizes, int n_in,
                              void* d_out, int out_size, void* d_ws, size_t ws_size,
                              hipStream_t stream)
{
    const float* x  = (const float*)d_in[0];
    const float* Wq = (const float*)d_in[1];
    const float* Wk = (const float*)d_in[2];
    const float* Wv = (const float*)d_in[3];
    float* out = (float*)d_out;

    const long long n = (long long)BB * TT * HH;   // 4,194,304
    unsigned short* qb = (unsigned short*)d_ws;
    unsigned short* Kf = qb + n;
    unsigned short* Vf = Kf + n;
    unsigned short* Ob = Vf + n;                   // 1024 * 16384 bf16 = 33.5 MB
    float*          Lb = (float*)(Ob + (long long)1024 * 16384);  // 1024*128 fp32

    qkv_mfma<<<BB * (TT / 64), NTH, 0, stream>>>(x, Wq, Wk, Wv, qb, Kf, Vf);
    flash_splitk<<<1024, 512, 0, stream>>>(qb, Kf, Vf, Ob, Lb);
    combine<<<BB * 64, NTH, 0, stream>>>(Ob, Lb, out);
}

// Round 10
// 151.566 us; speedup vs baseline: 1.7127x; 1.1343x over previous
//
#include <hip/hip_runtime.h>
#include <math.h>

// nanoGPT Head: x[B,T,C] @ W{q,k,v}[C,H] -> causal softmax(QK^T/sqrt(H)) V
#define BB 8
#define TT 4096
#define CC 64
#define HH 128
#define NTH 256
#define XSTR 72        // proj x stride (bf16)
#define WSTR 72        // proj W stride (bf16)
// 128^-0.5 * log2(e): folded into Wq so S-scores are in log2 domain
#define QSCALE ((float)(0.08838834764831845 * 1.4426950408889634))

typedef __attribute__((ext_vector_type(8)))  short short8;    // 8 bf16 (MFMA A/B frag)
typedef __attribute__((ext_vector_type(4)))  float floatx4;   // 16x16 C/D frag
typedef __attribute__((ext_vector_type(16))) float floatx16;  // 32x32 C/D frag

__device__ __forceinline__ unsigned short f2bf(float f) {
    union { float f; unsigned int u; } un; un.f = f;
    unsigned int r = un.u + 0x7FFF + ((un.u >> 16) & 1);   // RNE
    return (unsigned short)(r >> 16);
}
// fast bf16 pair pack: round-half-up + v_perm (3 VALU ops vs ~9)
__device__ __forceinline__ unsigned int pack2bf_fast(float a, float b) {
    union { float f; unsigned int u; } ua, ub; ua.f = a; ub.f = b;
    return __builtin_amdgcn_perm(ub.u + 0x8000u, ua.u + 0x8000u, 0x07060302u);
}
__device__ __forceinline__ float bflo(unsigned int u) {
    union { unsigned int u; float f; } x; x.u = u << 16; return x.f;
}
__device__ __forceinline__ float bfhi(unsigned int u) {
    union { unsigned int u; float f; } x; x.u = u & 0xffff0000u; return x.f;
}

// ---------------- Kernel 1: QKV projection via MFMA ----------------
// Q -> [B,T,H] row-major bf16.
// K -> fragment-tiled: 64-key tile t: 16 KB @ (b*64+t)*16384 B, halves kh at +kh*8192 B
// V -> fragment-tiled: 64-key tile t: 16 KB @ (b*64+t)*16384 B, halves kh at +kh*8192 B
__global__ __launch_bounds__(NTH) void qkv_mfma(
    const float* __restrict__ x,
    const float* __restrict__ Wq, const float* __restrict__ Wk, const float* __restrict__ Wv,
    unsigned short* __restrict__ qb, unsigned short* __restrict__ Kf,
    unsigned short* __restrict__ Vf)
{
    __shared__ __align__(16) unsigned short xs[64 * XSTR];
    __shared__ __align__(16) unsigned short Wts[3 * HH * WSTR];

    const int tid  = threadIdx.x;
    const int w    = tid >> 6;
    const int lane = tid & 63;
    const int quad = lane >> 4;
    const int lr   = lane & 15;

    const int b    = blockIdx.x >> 6;
    const int kblk = blockIdx.x & 63;
    const int t0   = kblk * 64;
    const long long rbase = (long long)b * TT + t0;

#pragma unroll
    for (int i = 0; i < 4; ++i) {
        const int idx = tid + i * NTH;
        const int r = idx >> 4, c4 = idx & 15;
        const float4 v = *(const float4*)(x + (rbase + r) * CC + c4 * 4);
        unsigned short tmp[4] = { f2bf(v.x), f2bf(v.y), f2bf(v.z), f2bf(v.w) };
        *(unsigned long long*)&xs[r * XSTR + c4 * 4] = *(unsigned long long*)tmp;
    }
#pragma unroll
    for (int mat = 0; mat < 3; ++mat) {
        const float* W = mat == 0 ? Wq : (mat == 1 ? Wk : Wv);
        const float s = mat == 0 ? QSCALE : 1.0f;
#pragma unroll
        for (int i = 0; i < 32; ++i) {
            const int idx = tid + i * NTH;
            const int c = idx >> 7, h = idx & 127;
            Wts[(mat * HH + h) * WSTR + c] = f2bf(W[idx] * s);
        }
    }
    __syncthreads();

    const short8 bx0 = *(const short8*)&xs[(w * 16 + lr) * XSTR + quad * 8];
    const short8 bx1 = *(const short8*)&xs[(w * 16 + lr) * XSTR + 32 + quad * 8];

    // Q
    {
        const unsigned short* Wrow = Wts;
#pragma unroll
        for (int ht = 0; ht < 8; ++ht) {
            const short8 aw0 = *(const short8*)(Wrow + (ht * 16 + lr) * WSTR + quad * 8);
            const short8 aw1 = *(const short8*)(Wrow + (ht * 16 + lr) * WSTR + 32 + quad * 8);
            floatx4 acc = (floatx4)0.f;
            acc = __builtin_amdgcn_mfma_f32_16x16x32_bf16(aw0, bx0, acc, 0, 0, 0);
            acc = __builtin_amdgcn_mfma_f32_16x16x32_bf16(aw1, bx1, acc, 0, 0, 0);
            ushort4 st = { f2bf(acc[0]), f2bf(acc[1]), f2bf(acc[2]), f2bf(acc[3]) };
            *(ushort4*)(qb + (rbase + w * 16 + lr) * HH + ht * 16 + quad * 4) = st;
        }
    }
    // K fragment-tiled
    {
        const unsigned short* Wrow = Wts + 1 * HH * WSTR;
        const int khp = w >> 1;
        const int lqp = (w & 1) * 16 + lr;
        unsigned short* kdst = Kf + ((long long)((b * 64 + kblk) * 2 + khp)) * 4096
                             + ((quad >> 1) & 1) * 256 + lqp * 8 + (quad & 1) * 4;
#pragma unroll
        for (int ht = 0; ht < 8; ++ht) {
            const short8 aw0 = *(const short8*)(Wrow + (ht * 16 + lr) * WSTR + quad * 8);
            const short8 aw1 = *(const short8*)(Wrow + (ht * 16 + lr) * WSTR + 32 + quad * 8);
            floatx4 acc = (floatx4)0.f;
            acc = __builtin_amdgcn_mfma_f32_16x16x32_bf16(aw0, bx0, acc, 0, 0, 0);
            acc = __builtin_amdgcn_mfma_f32_16x16x32_bf16(aw1, bx1, acc, 0, 0, 0);
            ushort4 st = { f2bf(acc[0]), f2bf(acc[1]), f2bf(acc[2]), f2bf(acc[3]) };
            *(ushort4*)(kdst + ht * 512) = st;
        }
    }
    // V fragment-tiled
    {
        const unsigned short* Wrow = Wts + 2 * HH * WSTR;
        const int khv = w >> 1, ksv = w & 1, lsv = (quad >> 1) & 1;
        unsigned short* vdst = Vf + (long long)(b * 64 + kblk) * 8192 + khv * 4096
                             + ksv * 512 + lsv * 256 + (quad & 1) * 4;
#pragma unroll
        for (int htp = 0; htp < 8; ++htp) {
            const short8 bw0 = *(const short8*)(Wrow + (htp * 16 + lr) * WSTR + quad * 8);
            const short8 bw1 = *(const short8*)(Wrow + (htp * 16 + lr) * WSTR + 32 + quad * 8);
            floatx4 acc = (floatx4)0.f;
            acc = __builtin_amdgcn_mfma_f32_16x16x32_bf16(bx0, bw0, acc, 0, 0, 0);
            acc = __builtin_amdgcn_mfma_f32_16x16x32_bf16(bx1, bw1, acc, 0, 0, 0);
            ushort4 st = { f2bf(acc[0]), f2bf(acc[1]), f2bf(acc[2]), f2bf(acc[3]) };
            *(ushort4*)(vdst + (htp >> 1) * 1024 + ((htp & 1) * 16 + lr) * 8) = st;
        }
    }
}

// ---------------- Kernel 2: split-K flash, direct global frag loads (R7 structure) ----------------
// Block = (qt, b, chunk c of 4), 4 waves: qh = w>>1 (32-q half), kh = w&1 (32-key half).
// b = id&7 pins each batch to one XCD's L2 under round-robin dispatch (4 MB K+V fits 4 MiB L2).
// __launch_bounds__(256,3): 170-reg budget (need ~176 at 2-wave) -> allocator shaves to fit,
// 3 waves/SIMD. exp2 via raw v_exp_f32 intrinsic (scores bounded, no fixup needed).
__global__ __launch_bounds__(NTH, 3) void flash_splitk(
    const unsigned short* __restrict__ qb,
    const unsigned short* __restrict__ Kf,
    const unsigned short* __restrict__ Vf,
    unsigned short* __restrict__ Ob, float* __restrict__ Lb)
{
    __shared__ __align__(16) float ex[2][64 * 68];
    __shared__ float Lx[4][32];

    const int tid  = threadIdx.x;
    const int w    = tid >> 6;
    const int lane = tid & 63;
    const int lq   = lane & 31;
    const int ls   = lane >> 5;
    const int kh   = w & 1;
    const int qh   = w >> 1;

    const int id  = blockIdx.x;
    const int b   = id & 7;               // XCD-pinned batch
    const int c   = (id >> 3) & 3;
    const int qt  = 63 - (id >> 5);       // heavy q-tiles dispatched first
    const int len = (qt + 4) >> 2;
    const int lo  = c * len;
    if (lo > qt) return;                  // empty chunk
    const int hi  = (lo + len - 1 < qt) ? (lo + len - 1) : qt;

    const int q0 = qt * 64;
    const long long baset = (long long)b * TT;

    const unsigned short* kptr = Kf + ((long long)(b * 128 + kh)) * 4096 + lane * 8;
    const unsigned short* vptr = Vf + ((long long)b * 64) * 8192 + kh * 4096 + lane * 8;

    // Q fragments: row q0+qh*32+lq, d = st*16 + ls*8 + j
    short8 aq[8];
    {
        const unsigned short* qrp = qb + (baset + q0 + qh * 32 + lq) * HH + ls * 8;
#pragma unroll
        for (int st = 0; st < 8; ++st)
            aq[st] = *(const short8*)(qrp + st * 16);
    }

    floatx16 o_acc[4];   // O^T partial: h = ht*32 + row(reg,ls), q = qh*32+lq (kh's keys only)
#pragma unroll
    for (int ht = 0; ht < 4; ++ht) o_acc[ht] = (floatx16)0.f;
    float l_lane = 0.f;

    for (int kt = lo; kt <= hi; ++kt) {
        const unsigned short* kp = kptr + (long long)kt * 8192;
        const unsigned short* vp = vptr + (long long)kt * 8192;

        const bool diag = (kt == qt);
        if (diag && kh > qh) continue;     // wave-tile fully masked

        short8 kfr[8], vfr[8];
#pragma unroll
        for (int st = 0; st < 8; ++st)
            kfr[st] = *(const short8*)(kp + st * 512);
#pragma unroll
        for (int i = 0; i < 8; ++i)                    // ht = i>>1, ks = i&1
            vfr[i] = *(const short8*)(vp + (i >> 1) * 1024 + (i & 1) * 512);

        // S^T = K Q^T
        floatx16 s_acc = (floatx16)0.f;
#pragma unroll
        for (int st = 0; st < 8; ++st)
            s_acc = __builtin_amdgcn_mfma_f32_32x32x16_bf16(kfr[st], aq[st], s_acc, 0, 0, 0);

        // p = exp2(s) (raw v_exp_f32), diag mask, l accumulation
        float p[16];
        if (diag && kh == qh) {
#pragma unroll
            for (int reg = 0; reg < 16; ++reg) {
                const int kk = (reg & 3) + 8 * (reg >> 2) + 4 * ls;
                p[reg] = (kk <= lq) ? __builtin_amdgcn_exp2f(s_acc[reg]) : 0.f;
            }
        } else {
#pragma unroll
            for (int reg = 0; reg < 16; ++reg)
                p[reg] = __builtin_amdgcn_exp2f(s_acc[reg]);
        }
#pragma unroll
        for (int reg = 0; reg < 16; ++reg) l_lane += p[reg];

        // P C-layout -> B-layout in-register
        unsigned int g[8], pg[8];
#pragma unroll
        for (int i = 0; i < 8; ++i) g[i] = pack2bf_fast(p[2 * i], p[2 * i + 1]);
#pragma unroll
        for (int i = 0; i < 8; ++i) pg[i] = __shfl_xor((int)g[i], 32);
        short8 bp[2];
#pragma unroll
        for (int ks = 0; ks < 2; ++ks) {
            union { short8 s; unsigned int u[4]; } fr;
            const int bs = ks * 4;
            if (ls == 0) {
                fr.u[0] = g[bs];      fr.u[1] = g[bs + 1];
                fr.u[2] = pg[bs];     fr.u[3] = pg[bs + 1];
            } else {
                fr.u[0] = pg[bs + 2]; fr.u[1] = pg[bs + 3];
                fr.u[2] = g[bs + 2];  fr.u[3] = g[bs + 3];
            }
            bp[ks] = fr.s;
        }

        // O^T += V^T P^T
#pragma unroll
        for (int ht = 0; ht < 4; ++ht) {
            o_acc[ht] = __builtin_amdgcn_mfma_f32_32x32x16_bf16(vfr[ht * 2 + 0], bp[0], o_acc[ht], 0, 0, 0);
            o_acc[ht] = __builtin_amdgcn_mfma_f32_32x32x16_bf16(vfr[ht * 2 + 1], bp[1], o_acc[ht], 0, 0, 0);
        }
    }

    // ---- epilogue: fold ls, exchange kh halves via LDS, write partial Ob + Lb ----
    const float l2 = l_lane + __shfl_xor(l_lane, 32);
    if (lane < 32) Lx[w][lq] = l2;
    if (kh == 1) {
        float* e = &ex[qh][lane * 68];
#pragma unroll
        for (int ht = 0; ht < 4; ++ht)
#pragma unroll
            for (int rg = 0; rg < 4; ++rg) {
                float4 v = make_float4(o_acc[ht][rg * 4 + 0], o_acc[ht][rg * 4 + 1],
                                       o_acc[ht][rg * 4 + 2], o_acc[ht][rg * 4 + 3]);
                *(float4*)&e[ht * 16 + rg * 4] = v;
            }
    }
    __syncthreads();
    if (kh == 0) {
        const int pid = ((b * 64 + qt) << 2) + c;
        Lb[pid * 64 + qh * 32 + lq] = Lx[2 * qh][lq] + Lx[2 * qh + 1][lq];
        const float* e = &ex[qh][lane * 68];
        unsigned short* od = Ob + (long long)pid * 8192 + (qh * 32 + lq) * HH;
#pragma unroll
        for (int ht = 0; ht < 4; ++ht)
#pragma unroll
            for (int rg = 0; rg < 4; ++rg) {
                const float4 pv = *(const float4*)&e[ht * 16 + rg * 4];
                uint2 st;
                st.x = pack2bf_fast(o_acc[ht][rg * 4 + 0] + pv.x, o_acc[ht][rg * 4 + 1] + pv.y);
                st.y = pack2bf_fast(o_acc[ht][rg * 4 + 2] + pv.z, o_acc[ht][rg * 4 + 3] + pv.w);
                *(uint2*)(od + ht * 32 + rg * 8 + 4 * ls) = st;
            }
    }
}

// ---------------- Kernel 3: combine partials, divide by l ----------------
// Block = (b,qt); thread t: q = t>>2, h-group (t&3)*32. Sums <=4 partials, writes out fp32.
__global__ __launch_bounds__(NTH) void combine(
    const unsigned short* __restrict__ Ob, const float* __restrict__ Lb,
    float* __restrict__ out)
{
    const int id = blockIdx.x;
    const int b = id & 7, qt = id >> 3;
    const int len = (qt + 4) >> 2;
    const int tid = threadIdx.x;
    const int q = tid >> 2;
    const int hg = tid & 3;
    const int pid0 = (b * 64 + qt) << 2;

    float acc[32];
#pragma unroll
    for (int i = 0; i < 32; ++i) acc[i] = 0.f;
    float ltot = 0.f;

#pragma unroll
    for (int c = 0; c < 4; ++c) {
        if (c * len > qt) break;
        ltot += Lb[(pid0 + c) * 64 + q];
        const uint4* src = (const uint4*)(Ob + (long long)(pid0 + c) * 8192 + q * HH + hg * 32);
#pragma unroll
        for (int g = 0; g < 4; ++g) {
            const uint4 d = src[g];
            acc[g * 8 + 0] += bflo(d.x); acc[g * 8 + 1] += bfhi(d.x);
            acc[g * 8 + 2] += bflo(d.y); acc[g * 8 + 3] += bfhi(d.y);
            acc[g * 8 + 4] += bflo(d.z); acc[g * 8 + 5] += bfhi(d.z);
            acc[g * 8 + 6] += bflo(d.w); acc[g * 8 + 7] += bfhi(d.w);
        }
    }
    const float inv = 1.f / ltot;
    float* op = out + ((long long)b * TT + qt * 64 + q) * HH + hg * 32;
#pragma unroll
    for (int g = 0; g < 8; ++g) {
        float4 st = make_float4(acc[g * 4 + 0] * inv, acc[g * 4 + 1] * inv,
                                acc[g * 4 + 2] * inv, acc[g * 4 + 3] * inv);
        *(float4*)(op + g * 4) = st;
    }
}

extern "C" void kernel_launch(void* const* d_in, const int* in_sizes, int n_in,
                              void* d_out, int out_size, void* d_ws, size_t ws_size,
                              hipStream_t stream)
{
    const float* x  = (const float*)d_in[0];
    const float* Wq = (const float*)d_in[1];
    const float* Wk = (const float*)d_in[2];
    const float* Wv = (const float*)d_in[3];
    float* out = (float*)d_out;

    const long long n = (long long)BB * TT * HH;   // 4,194,304
    unsigned short* qb = (unsigned short*)d_ws;
    unsigned short* Kf = qb + n;
    unsigned short* Vf = Kf + n;
    unsigned short* Ob = Vf + n;                   // 2048 * 8192 bf16 = 33.5 MB
    float*          Lb = (float*)(Ob + (long long)2048 * 8192);  // 2048*64 fp32

    qkv_mfma<<<BB * (TT / 64), NTH, 0, stream>>>(x, Wq, Wk, Wv, qb, Kf, Vf);
    flash_splitk<<<2048, NTH, 0, stream>>>(qb, Kf, Vf, Ob, Lb);
    combine<<<BB * 64, NTH, 0, stream>>>(Ob, Lb, out);
}

// Round 11
// 144.041 us; speedup vs baseline: 1.8022x; 1.0522x over previous
//
#include <hip/hip_runtime.h>
#include <math.h>

// nanoGPT Head: x[B,T,C] @ W{q,k,v}[C,H] -> causal softmax(QK^T/sqrt(H)) V
#define BB 8
#define TT 4096
#define CC 64
#define HH 128
#define NTH 256
#define XSTR 72        // proj x stride (bf16)
#define WSTR 72        // proj W stride (bf16)
// 128^-0.5 * log2(e): folded into Wq so S-scores are in log2 domain
#define QSCALE ((float)(0.08838834764831845 * 1.4426950408889634))

typedef __attribute__((ext_vector_type(8)))  short short8;    // 8 bf16 (MFMA A/B frag)
typedef __attribute__((ext_vector_type(4)))  float floatx4;   // 16x16 C/D frag
typedef __attribute__((ext_vector_type(16))) float floatx16;  // 32x32 C/D frag

__device__ __forceinline__ unsigned short f2bf(float f) {
    union { float f; unsigned int u; } un; un.f = f;
    unsigned int r = un.u + 0x7FFF + ((un.u >> 16) & 1);   // RNE
    return (unsigned short)(r >> 16);
}
// fast bf16 pair pack: round-half-up + v_perm (3 VALU ops)
__device__ __forceinline__ unsigned int pack2bf_fast(float a, float b) {
    union { float f; unsigned int u; } ua, ub; ua.f = a; ub.f = b;
    return __builtin_amdgcn_perm(ub.u + 0x8000u, ua.u + 0x8000u, 0x07060302u);
}
__device__ __forceinline__ float bflo(unsigned int u) {
    union { unsigned int u; float f; } x; x.u = u << 16; return x.f;
}
__device__ __forceinline__ float bfhi(unsigned int u) {
    union { unsigned int u; float f; } x; x.u = u & 0xffff0000u; return x.f;
}

// async global->LDS, 16B per lane; lds dest = wave-uniform base + lane*16
__device__ __forceinline__ void gl_lds16(const void* g, void* l) {
    __builtin_amdgcn_global_load_lds(
        (const __attribute__((address_space(1))) unsigned int*)g,
        (__attribute__((address_space(3))) unsigned int*)l, 16, 0, 0);
}

// ---------------- Kernel 1: QKV projection via MFMA (unchanged from R10) ----------------
// Q -> [B,T,H] row-major bf16.
// K -> fragment-tiled: 32-key half j (8192 B) @ (b*128+j)*8192 B;
//      within: st*1024 + lane*16 B holds K[j*32+(lane&31)][st*16+(lane>>5)*8 ..+8]
// V -> fragment-tiled: 32-key half j (8192 B) @ b*64*16384 + j*8192 B;
//      within: ht*2048 + ks*1024 + lane*16 B holds V^T[ht*32+(lane&31)][j*32+ks*16+(lane>>5)*8 ..+8]
__global__ __launch_bounds__(NTH) void qkv_mfma(
    const float* __restrict__ x,
    const float* __restrict__ Wq, const float* __restrict__ Wk, const float* __restrict__ Wv,
    unsigned short* __restrict__ qb, unsigned short* __restrict__ Kf,
    unsigned short* __restrict__ Vf)
{
    __shared__ __align__(16) unsigned short xs[64 * XSTR];
    __shared__ __align__(16) unsigned short Wts[3 * HH * WSTR];

    const int tid  = threadIdx.x;
    const int w    = tid >> 6;
    const int lane = tid & 63;
    const int quad = lane >> 4;
    const int lr   = lane & 15;

    const int b    = blockIdx.x >> 6;
    const int kblk = blockIdx.x & 63;
    const int t0   = kblk * 64;
    const long long rbase = (long long)b * TT + t0;

#pragma unroll
    for (int i = 0; i < 4; ++i) {
        const int idx = tid + i * NTH;
        const int r = idx >> 4, c4 = idx & 15;
        const float4 v = *(const float4*)(x + (rbase + r) * CC + c4 * 4);
        unsigned short tmp[4] = { f2bf(v.x), f2bf(v.y), f2bf(v.z), f2bf(v.w) };
        *(unsigned long long*)&xs[r * XSTR + c4 * 4] = *(unsigned long long*)tmp;
    }
#pragma unroll
    for (int mat = 0; mat < 3; ++mat) {
        const float* W = mat == 0 ? Wq : (mat == 1 ? Wk : Wv);
        const float s = mat == 0 ? QSCALE : 1.0f;
#pragma unroll
        for (int i = 0; i < 32; ++i) {
            const int idx = tid + i * NTH;
            const int c = idx >> 7, h = idx & 127;
            Wts[(mat * HH + h) * WSTR + c] = f2bf(W[idx] * s);
        }
    }
    __syncthreads();

    const short8 bx0 = *(const short8*)&xs[(w * 16 + lr) * XSTR + quad * 8];
    const short8 bx1 = *(const short8*)&xs[(w * 16 + lr) * XSTR + 32 + quad * 8];

    // Q
    {
        const unsigned short* Wrow = Wts;
#pragma unroll
        for (int ht = 0; ht < 8; ++ht) {
            const short8 aw0 = *(const short8*)(Wrow + (ht * 16 + lr) * WSTR + quad * 8);
            const short8 aw1 = *(const short8*)(Wrow + (ht * 16 + lr) * WSTR + 32 + quad * 8);
            floatx4 acc = (floatx4)0.f;
            acc = __builtin_amdgcn_mfma_f32_16x16x32_bf16(aw0, bx0, acc, 0, 0, 0);
            acc = __builtin_amdgcn_mfma_f32_16x16x32_bf16(aw1, bx1, acc, 0, 0, 0);
            ushort4 st = { f2bf(acc[0]), f2bf(acc[1]), f2bf(acc[2]), f2bf(acc[3]) };
            *(ushort4*)(qb + (rbase + w * 16 + lr) * HH + ht * 16 + quad * 4) = st;
        }
    }
    // K fragment-tiled
    {
        const unsigned short* Wrow = Wts + 1 * HH * WSTR;
        const int khp = w >> 1;
        const int lqp = (w & 1) * 16 + lr;
        unsigned short* kdst = Kf + ((long long)((b * 64 + kblk) * 2 + khp)) * 4096
                             + ((quad >> 1) & 1) * 256 + lqp * 8 + (quad & 1) * 4;
#pragma unroll
        for (int ht = 0; ht < 8; ++ht) {
            const short8 aw0 = *(const short8*)(Wrow + (ht * 16 + lr) * WSTR + quad * 8);
            const short8 aw1 = *(const short8*)(Wrow + (ht * 16 + lr) * WSTR + 32 + quad * 8);
            floatx4 acc = (floatx4)0.f;
            acc = __builtin_amdgcn_mfma_f32_16x16x32_bf16(aw0, bx0, acc, 0, 0, 0);
            acc = __builtin_amdgcn_mfma_f32_16x16x32_bf16(aw1, bx1, acc, 0, 0, 0);
            ushort4 st = { f2bf(acc[0]), f2bf(acc[1]), f2bf(acc[2]), f2bf(acc[3]) };
            *(ushort4*)(kdst + ht * 512) = st;
        }
    }
    // V fragment-tiled
    {
        const unsigned short* Wrow = Wts + 2 * HH * WSTR;
        const int khv = w >> 1, ksv = w & 1, lsv = (quad >> 1) & 1;
        unsigned short* vdst = Vf + (long long)(b * 64 + kblk) * 8192 + khv * 4096
                             + ksv * 512 + lsv * 256 + (quad & 1) * 4;
#pragma unroll
        for (int htp = 0; htp < 8; ++htp) {
            const short8 bw0 = *(const short8*)(Wrow + (htp * 16 + lr) * WSTR + quad * 8);
            const short8 bw1 = *(const short8*)(Wrow + (htp * 16 + lr) * WSTR + 32 + quad * 8);
            floatx4 acc = (floatx4)0.f;
            acc = __builtin_amdgcn_mfma_f32_16x16x32_bf16(bx0, bw0, acc, 0, 0, 0);
            acc = __builtin_amdgcn_mfma_f32_16x16x32_bf16(bx1, bw1, acc, 0, 0, 0);
            ushort4 st = { f2bf(acc[0]), f2bf(acc[1]), f2bf(acc[2]), f2bf(acc[3]) };
            *(ushort4*)(vdst + (htp >> 1) * 1024 + ((htp & 1) * 16 + lr) * 8) = st;
        }
    }
}

// stage one 32-key tile (K 8KB + V 8KB) into LDS; 4 waves x 4KB each
__device__ __forceinline__ void dma_tile32(
    const unsigned char* __restrict__ Kj, const unsigned char* __restrict__ Vj,
    unsigned char* buf, int w, int lane)
{
    const unsigned char* src;
    unsigned char* dst;
    if (w < 2) { src = Kj + w * 4096 + lane * 16;        dst = buf + w * 4096; }
    else       { src = Vj + (w - 2) * 4096 + lane * 16;  dst = buf + 8192 + (w - 2) * 4096; }
#pragma unroll
    for (int i = 0; i < 4; ++i)
        gl_lds16(src + i * 1024, dst + i * 1024);
}

// ---------------- Kernel 2: split-K flash, LDS-staged 32k tiles, 4 q-waves ----------------
// Block = (b, 128-q tile, chunk c of 4). Waves = q-quarters (qh=0..3); keys split across
// blocks only -> no cross-wave epilogue. len = qt+1 exactly (no empty blocks).
// 32x32x16: A[m=lane&31][k=(lane>>5)*8+j]; B[k][n=lane&31]; C/D: col=lane&31,
// row=(reg&3)+8*(reg>>2)+4*(lane>>5). No-max softmax (log2-domain scores via Wq).
__global__ __launch_bounds__(NTH, 3) void flash_splitk(
    const unsigned short* __restrict__ qb,
    const unsigned short* __restrict__ Kf,
    const unsigned short* __restrict__ Vf,
    unsigned short* __restrict__ Ob, float* __restrict__ Lb)
{
    __shared__ __align__(16) unsigned char KV[2][16384];   // [buf][K 8KB | V 8KB]

    const int tid  = threadIdx.x;
    const int w    = tid >> 6;        // qh
    const int lane = tid & 63;
    const int lq   = lane & 31;
    const int ls   = lane >> 5;

    const int id = blockIdx.x;
    const int b  = id & 7;                        // XCD-pinned batch
    const int c  = (id >> 3) & 3;
    const int qt = 31 - (id >> 5);                // heavy q-tiles first
    const int len = qt + 1;                       // ntiles = 4*(qt+1), split exactly by 4
    const int lo  = c * len;
    const int hi  = lo + qt;                      // lo + len - 1

    const int q0 = qt * 128;
    const long long baset = (long long)b * TT;
    const unsigned char* Kbase = (const unsigned char*)Kf + (long long)b * 128 * 8192;
    const unsigned char* Vbase = (const unsigned char*)Vf + (long long)b * 128 * 8192;

    dma_tile32(Kbase + (long long)lo * 8192, Vbase + (long long)lo * 8192, KV[0], w, lane);

    // Q fragments: row q0 + w*32 + lq, d = st*16 + ls*8 + j
    short8 aq[8];
    {
        const unsigned short* qrp = qb + (baset + q0 + w * 32 + lq) * HH + ls * 8;
#pragma unroll
        for (int st = 0; st < 8; ++st)
            aq[st] = *(const short8*)(qrp + st * 16);
    }

    floatx16 o_acc[4];   // O^T partial: h = ht*32 + row(reg,ls), q = w*32+lq
#pragma unroll
    for (int ht = 0; ht < 4; ++ht) o_acc[ht] = (floatx16)0.f;
    float l_lane = 0.f;

    for (int j = lo; j <= hi; ++j) {
        const int cb = (j - lo) & 1;
        __syncthreads();   // compiler vmcnt(0) drains buf[cb] DMA; prior readers of buf[cb^1] done
        if (j < hi)        // prefetch next tile: in flight across this whole iteration
            dma_tile32(Kbase + (long long)(j + 1) * 8192, Vbase + (long long)(j + 1) * 8192,
                       KV[cb ^ 1], w, lane);

        const int D = q0 + w * 32 - j * 32;       // q_start - k_start (wave-uniform)
        if (D > -32) {
            const unsigned short* Kt = (const unsigned short*)&KV[cb][0];
            const unsigned short* Vt = (const unsigned short*)&KV[cb][8192];

            short8 kfr[8], vfr[8];
#pragma unroll
            for (int st = 0; st < 8; ++st)
                kfr[st] = *(const short8*)(Kt + st * 512 + lane * 8);
#pragma unroll
            for (int i = 0; i < 8; ++i)           // ht = i>>1, ks = i&1
                vfr[i] = *(const short8*)(Vt + (i >> 1) * 1024 + (i & 1) * 512 + lane * 8);

            // S^T = K Q^T
            floatx16 s_acc = (floatx16)0.f;
#pragma unroll
            for (int st = 0; st < 8; ++st)
                s_acc = __builtin_amdgcn_mfma_f32_32x32x16_bf16(kfr[st], aq[st], s_acc, 0, 0, 0);

            // p = exp2(s) (raw v_exp_f32), causal mask (kk <= lq + D), l accumulation
            float p[16];
            if (D < 31) {
#pragma unroll
                for (int reg = 0; reg < 16; ++reg) {
                    const int kk = (reg & 3) + 8 * (reg >> 2) + 4 * ls;
                    p[reg] = (kk <= lq + D) ? __builtin_amdgcn_exp2f(s_acc[reg]) : 0.f;
                }
            } else {
#pragma unroll
                for (int reg = 0; reg < 16; ++reg)
                    p[reg] = __builtin_amdgcn_exp2f(s_acc[reg]);
            }
#pragma unroll
            for (int reg = 0; reg < 16; ++reg) l_lane += p[reg];

            // P C-layout -> B-layout in-register (ls-pair exchange)
            unsigned int g[8], pg[8];
#pragma unroll
            for (int i = 0; i < 8; ++i) g[i] = pack2bf_fast(p[2 * i], p[2 * i + 1]);
#pragma unroll
            for (int i = 0; i < 8; ++i) pg[i] = __shfl_xor((int)g[i], 32);
            short8 bp[2];
#pragma unroll
            for (int ks = 0; ks < 2; ++ks) {
                union { short8 s; unsigned int u[4]; } fr;
                const int bs = ks * 4;
                if (ls == 0) {
                    fr.u[0] = g[bs];      fr.u[1] = g[bs + 1];
                    fr.u[2] = pg[bs];     fr.u[3] = pg[bs + 1];
                } else {
                    fr.u[0] = pg[bs + 2]; fr.u[1] = pg[bs + 3];
                    fr.u[2] = g[bs + 2];  fr.u[3] = g[bs + 3];
                }
                bp[ks] = fr.s;
            }

            // O^T += V^T P^T
#pragma unroll
            for (int ht = 0; ht < 4; ++ht) {
                o_acc[ht] = __builtin_amdgcn_mfma_f32_32x32x16_bf16(vfr[ht * 2 + 0], bp[0], o_acc[ht], 0, 0, 0);
                o_acc[ht] = __builtin_amdgcn_mfma_f32_32x32x16_bf16(vfr[ht * 2 + 1], bp[1], o_acc[ht], 0, 0, 0);
            }
        }
    }

    // ---- epilogue: wave-local; fold ls halves of l, write raw partial O + l ----
    const int pid = ((b * 32 + qt) << 2) + c;
    const float l2 = l_lane + __shfl_xor(l_lane, 32);
    if (lane < 32) Lb[pid * 128 + w * 32 + lq] = l2;

    unsigned short* od = Ob + (long long)pid * 16384 + (w * 32 + lq) * HH;
#pragma unroll
    for (int ht = 0; ht < 4; ++ht)
#pragma unroll
        for (int rg = 0; rg < 4; ++rg) {
            uint2 st;
            st.x = pack2bf_fast(o_acc[ht][rg * 4 + 0], o_acc[ht][rg * 4 + 1]);
            st.y = pack2bf_fast(o_acc[ht][rg * 4 + 2], o_acc[ht][rg * 4 + 3]);
            *(uint2*)(od + ht * 32 + rg * 8 + 4 * ls) = st;
        }
}

// ---------------- Kernel 3: combine 4 chunk partials, divide by l ----------------
// Block = (b, qt128, 64-q half); thread t: q = t>>2 within half, h-group (t&3)*32.
__global__ __launch_bounds__(NTH) void combine(
    const unsigned short* __restrict__ Ob, const float* __restrict__ Lb,
    float* __restrict__ out)
{
    const int id = blockIdx.x;
    const int b = id & 7;
    const int rest = id >> 3;                  // 0..63
    const int qt = rest >> 1, half = rest & 1;
    const int tid = threadIdx.x;
    const int q = half * 64 + (tid >> 2);      // 0..127 within tile
    const int hg = tid & 3;
    const int pid0 = ((b * 32 + qt) << 2);

    float acc[32];
#pragma unroll
    for (int i = 0; i < 32; ++i) acc[i] = 0.f;
    float ltot = 0.f;

#pragma unroll
    for (int c = 0; c < 4; ++c) {
        ltot += Lb[(pid0 + c) * 128 + q];
        const uint4* src = (const uint4*)(Ob + (long long)(pid0 + c) * 16384 + q * HH + hg * 32);
#pragma unroll
        for (int g = 0; g < 4; ++g) {
            const uint4 d = src[g];
            acc[g * 8 + 0] += bflo(d.x); acc[g * 8 + 1] += bfhi(d.x);
            acc[g * 8 + 2] += bflo(d.y); acc[g * 8 + 3] += bfhi(d.y);
            acc[g * 8 + 4] += bflo(d.z); acc[g * 8 + 5] += bfhi(d.z);
            acc[g * 8 + 6] += bflo(d.w); acc[g * 8 + 7] += bfhi(d.w);
        }
    }
    const float inv = 1.f / ltot;
    float* op = out + ((long long)b * TT + qt * 128 + q) * HH + hg * 32;
#pragma unroll
    for (int g = 0; g < 8; ++g) {
        float4 st = make_float4(acc[g * 4 + 0] * inv, acc[g * 4 + 1] * inv,
                                acc[g * 4 + 2] * inv, acc[g * 4 + 3] * inv);
        *(float4*)(op + g * 4) = st;
    }
}

extern "C" void kernel_launch(void* const* d_in, const int* in_sizes, int n_in,
                              void* d_out, int out_size, void* d_ws, size_t ws_size,
                              hipStream_t stream)
{
    const float* x  = (const float*)d_in[0];
    const float* Wq = (const float*)d_in[1];
    const float* Wk = (const float*)d_in[2];
    const float* Wv = (const float*)d_in[3];
    float* out = (float*)d_out;

    const long long n = (long long)BB * TT * HH;   // 4,194,304
    unsigned short* qb = (unsigned short*)d_ws;
    unsigned short* Kf = qb + n;
    unsigned short* Vf = Kf + n;
    unsigned short* Ob = Vf + n;                   // 1024 * 16384 bf16 = 33.5 MB
    float*          Lb = (float*)(Ob + (long long)1024 * 16384);  // 1024*128 fp32

    qkv_mfma<<<BB * (TT / 64), NTH, 0, stream>>>(x, Wq, Wk, Wv, qb, Kf, Vf);
    flash_splitk<<<1024, NTH, 0, stream>>>(qb, Kf, Vf, Ob, Lb);
    combine<<<BB * 64, NTH, 0, stream>>>(Ob, Lb, out);
}